// Round 3
// baseline (2285.163 us; speedup 1.0000x reference)
//
#include <hip/hip_runtime.h>

typedef _Float16 f16;
typedef _Float16 f16x8 __attribute__((ext_vector_type(8)));
typedef _Float16 f16x4 __attribute__((ext_vector_type(4)));
typedef float    f32x4 __attribute__((ext_vector_type(4)));

#define MFMA32(a,b,c) __builtin_amdgcn_mfma_f32_16x16x32_f16((a),(b),(c),0,0,0)
#define MFMA16(a,b,c) __builtin_amdgcn_mfma_f32_16x16x16f16((a),(b),(c),0,0,0)

__device__ __forceinline__ f32x4 zero4() { f32x4 v = {0.f,0.f,0.f,0.f}; return v; }
#define ZERO44(A) { _Pragma("unroll") for (int z1=0;z1<4;++z1){ _Pragma("unroll") for (int z2=0;z2<4;++z2) A[z1][z2] = zero4(); } }

// ---- workspace layout ----
constexpr size_t OFF_PROJ = 0;        // [256][160] (K 158 padded to 160)
constexpr size_t OFF_QW  = 40960;     // [256][256]
constexpr size_t OFF_KW  = 106496;
constexpr size_t OFF_VW  = 172032;
constexpr size_t OFF_OW  = 237568;
constexpr size_t OFF_F1  = 303104;
constexpr size_t OFF_F2  = 368640;
constexpr size_t OFF_TA  = 434176;
constexpr size_t OFF_SQW = 499712;    // [256][288]
constexpr size_t OFF_SKW = 573440;    // [256][288]
constexpr size_t OFF_SVW = 647168;    // [256][256]
constexpr size_t OFF_SOW = 712704;
constexpr size_t OFF_SF1 = 778240;
constexpr size_t OFF_SF2 = 843776;
constexpr size_t W_ELEMS = 909312;
constexpr size_t PE_B  = W_ELEMS*2;             // pos-enc 64*256 f32
constexpr size_t Z_B   = PE_B  + 64*256*4;      // z    4096*256 f32
constexpr size_t QK_B  = Z_B   + 4096ull*256*4; // qk_in 4096*288 f16
constexpr size_t SQ_B  = QK_B  + 4096ull*288*2; // sq   4096*256 f16 (pre-scaled 0.125)
constexpr size_t SK_B  = SQ_B  + 4096ull*256*2; // sk
constexpr size_t SVT_B = SK_B  + 4096ull*256*2; // svT [256][4096] f16
constexpr size_t SO_B  = SVT_B + 4096ull*256*2; // so   4096*256 f16

// ---------------- prep: transpose weights to f16 WT, build pos-enc -------------
struct PrepArgs {
  const float* src[14];
  int K[14]; int Kp[14]; int off[14];
};

__global__ void prep_kernel(PrepArgs a, f16* __restrict__ wbuf, float* __restrict__ pe) {
  int wsel = blockIdx.y;
  int tid = threadIdx.x;
  if (wsel < 14) {
    const float* S = a.src[wsel];
    int K = a.K[wsel], Kp = a.Kp[wsel];
    f16* D = wbuf + a.off[wsel];
    int n = blockIdx.x*4 + (tid & 3);
    for (int k = (tid >> 2); k < Kp; k += 64) {
      float v = (k < K) ? S[(size_t)k*256 + n] : 0.f;
      D[(size_t)n*Kp + k] = (f16)v;
    }
  } else {
    int idx = blockIdx.x*256 + tid;       // gridDim.x = 64 -> 16384 = 64*256
    int t = idx >> 8, d = idx & 255, i = d >> 1;
    float div = expf((float)(2*i) * (-9.210340371976184f/256.f));
    float ang = (float)t * div;
    pe[idx] = (d & 1) ? cosf(ang) : sinf(ang);
  }
}

// ---------------- shared helpers ----------------
// vectorized LN over 64 rows x 256 cols (f16 LDS -> f16 LDS, src may == dst)
__device__ __forceinline__ void ln64v(f16 (*src)[264], f16 (*dst)[264],
    const float* __restrict__ sc, const float* __restrict__ bi, int w, int lane) {
  int row = w*16 + (lane >> 2);
  int c0 = lane & 3;               // lane covers cols j*32 + c0*8 .. +8
  f16x8 v[8];
  float s = 0.f, s2 = 0.f;
  #pragma unroll
  for (int j = 0; j < 8; ++j) {
    v[j] = *(const f16x8*)&src[row][j*32 + c0*8];
    #pragma unroll
    for (int e = 0; e < 8; ++e) { float f = (float)v[j][e]; s += f; s2 += f*f; }
  }
  s  += __shfl_xor(s, 1);  s  += __shfl_xor(s, 2);
  s2 += __shfl_xor(s2, 1); s2 += __shfl_xor(s2, 2);
  float mean = s * (1.f/256.f);
  float rstd = rsqrtf(s2 * (1.f/256.f) - mean*mean + 1e-5f);
  #pragma unroll
  for (int j = 0; j < 8; ++j) {
    int c = j*32 + c0*8;
    f16x8 o;
    #pragma unroll
    for (int e = 0; e < 8; ++e)
      o[e] = (f16)(((float)v[j][e] - mean) * rstd * sc[c+e] + bi[c+e]);
    *(f16x8*)&dst[row][c] = o;
  }
}

// C[64x64chunk] += A(LDS rows t, k contig) @ B(WT global), wave w owns cols [64w,64w+64)
template<int KSTEPS, int LDB>
__device__ __forceinline__ void gemm_ldsA(f16 (*A)[264], const f16* __restrict__ B,
                                          f32x4 (&acc)[4][4], int w, int l15, int g) {
  #pragma unroll
  for (int ks = 0; ks < KSTEPS; ++ks) {
    int kc = ks*32 + g*8;
    f16x8 av[4], bv[4];
    #pragma unroll
    for (int j = 0; j < 4; ++j) av[j] = *(const f16x8*)&A[j*16 + l15][kc];
    #pragma unroll
    for (int j = 0; j < 4; ++j) bv[j] = *(const f16x8*)(B + (size_t)(w*64 + j*16 + l15)*LDB + kc);
    #pragma unroll
    for (int mt = 0; mt < 4; ++mt) {
      #pragma unroll
      for (int nt = 0; nt < 4; ++nt)
        acc[mt][nt] = MFMA32(av[mt], bv[nt], acc[mt][nt]);
    }
  }
}

// FFN with LDS residual (used by final_kernel only)
__device__ __forceinline__ void ffn_block(f16 (*res)[264], f16 (*y)[264], f16 (*u)[72],
    const f16* __restrict__ W1, const f16* __restrict__ W2,
    const float* __restrict__ b1, const float* __restrict__ b2,
    int w, int l15, int g) {
  f32x4 acc2[4][4]; ZERO44(acc2);
  for (int ch = 0; ch < 4; ++ch) {
    f32x4 ua[4];
    #pragma unroll
    for (int nt = 0; nt < 4; ++nt) ua[nt] = zero4();
    #pragma unroll
    for (int ks = 0; ks < 8; ++ks) {
      int kc = ks*32 + g*8;
      f16x8 av = *(const f16x8*)&y[w*16 + l15][kc];
      f16x8 bv[4];
      #pragma unroll
      for (int j = 0; j < 4; ++j) bv[j] = *(const f16x8*)(W1 + (size_t)(ch*64 + j*16 + l15)*256 + kc);
      #pragma unroll
      for (int nt = 0; nt < 4; ++nt) ua[nt] = MFMA32(av, bv[nt], ua[nt]);
    }
    __syncthreads();
    #pragma unroll
    for (int nt = 0; nt < 4; ++nt) {
      int col = nt*16 + l15;
      #pragma unroll
      for (int i = 0; i < 4; ++i) {
        float v = ua[nt][i] + b1[ch*64 + col];
        u[w*16 + g*4 + i][col] = (f16)fmaxf(v, 0.f);
      }
    }
    __syncthreads();
    #pragma unroll
    for (int ks = 0; ks < 2; ++ks) {
      int kc = ks*32 + g*8;
      f16x8 av[4], bv[4];
      #pragma unroll
      for (int j = 0; j < 4; ++j) av[j] = *(const f16x8*)&u[j*16 + l15][kc];
      #pragma unroll
      for (int j = 0; j < 4; ++j) bv[j] = *(const f16x8*)(W2 + (size_t)(w*64 + j*16 + l15)*256 + ch*64 + kc);
      #pragma unroll
      for (int mt = 0; mt < 4; ++mt) {
        #pragma unroll
        for (int nt = 0; nt < 4; ++nt)
          acc2[mt][nt] = MFMA32(av[mt], bv[nt], acc2[mt][nt]);
      }
    }
  }
  #pragma unroll
  for (int mt = 0; mt < 4; ++mt) {
    #pragma unroll
    for (int nt = 0; nt < 4; ++nt) {
      int col = w*64 + nt*16 + l15;
      #pragma unroll
      for (int i = 0; i < 4; ++i) {
        int row = mt*16 + g*4 + i;
        float v = (float)res[row][col] + acc2[mt][nt][i] + b2[col];
        res[row][col] = (f16)v;
      }
    }
  }
}

// ---------------- K1: fused temporal transformer, one block per stock ----------
// Single LDS buffer; residual in registers (f16 C-frag layout); attention is
// chunked (kd-split QK, ks-split PV) so the live register set fits 170 VGPRs.
__global__ __launch_bounds__(256, 3) void temporal_kernel(
    const float* __restrict__ stock, const float* __restrict__ market,
    const float* __restrict__ gate_w, const float* __restrict__ gate_b,
    const float* __restrict__ proj_b, const float* __restrict__ t_ob,
    const float* __restrict__ t_nx_s, const float* __restrict__ t_nx_b,
    const float* __restrict__ t_nf_s, const float* __restrict__ t_nf_b,
    const float* __restrict__ t_f1b, const float* __restrict__ t_f2b,
    const f16* __restrict__ wbuf, const float* __restrict__ pe,
    float* __restrict__ zout)
{
  __shared__ __align__(16) f16 B[64][264];    // gated-feat / x / xs / O / y / zt / h
  __shared__ __align__(16) f16 ub[64][72];    // FFN hidden chunk
  __shared__ float gatev[160];
  __shared__ float mkt[64];
  __shared__ float red[66];

  const int tid = threadIdx.x;
  const int lane = tid & 63;
  const int w = tid >> 6;
  const int l15 = lane & 15;
  const int g = lane >> 4;
  const int n = blockIdx.x;

  f16x4 xres[4][4];   // residual: [row=mt*16+g*4+i][col=w*64+nt*16+l15]

  // ---- market gate: 158 * softmax(mkt @ gate_w + gate_b) ----
  if (tid < 64) mkt[tid] = market[(size_t)n*4096 + 63*64 + tid];
  __syncthreads();
  float logit = 0.f;
  if (tid < 158) {
    float acc = gate_b[tid];
    for (int m = 0; m < 64; ++m) acc += mkt[m] * gate_w[m*158 + tid];
    logit = acc;
  }
  if (tid < 160) gatev[tid] = (tid < 158) ? logit : -1e30f;
  __syncthreads();
  if (w == 0) {
    float v = fmaxf(gatev[lane], gatev[lane + 64]);
    if (lane < 32) v = fmaxf(v, gatev[lane + 128]);
    #pragma unroll
    for (int off = 32; off >= 1; off >>= 1) v = fmaxf(v, __shfl_xor(v, off));
    if (lane == 0) red[0] = v;
  }
  __syncthreads();
  float gmax = red[0];
  float ev = (tid < 158) ? __expf(logit - gmax) : 0.f;
  if (tid < 160) gatev[tid] = ev;
  __syncthreads();
  if (w == 0) {
    float v = gatev[lane] + gatev[lane + 64] + ((lane < 32) ? gatev[lane + 128] : 0.f);
    #pragma unroll
    for (int off = 32; off >= 1; off >>= 1) v += __shfl_xor(v, off);
    if (lane == 0) red[1] = v;
  }
  __syncthreads();
  const float grs = 158.f / red[1];

  // ---- gated stock features -> B, K padded to 160 ----
  for (int idx = tid; idx < 64*158; idx += 256) {
    int t = idx / 158, f = idx - t*158;
    B[t][f] = (f16)(stock[(size_t)n*(64*158) + idx] * (gatev[f] * grs));
  }
  if (tid < 128) B[tid >> 1][158 + (tid & 1)] = (f16)0.f;
  __syncthreads();

  // ---- x = gated @ proj_w + proj_b + pe -> xres + B ----
  {
    f32x4 acc[4][4]; ZERO44(acc);
    gemm_ldsA<5,160>(B, wbuf + OFF_PROJ, acc, w, l15, g);
    __syncthreads();   // all waves done reading gated features
    #pragma unroll
    for (int mt = 0; mt < 4; ++mt) {
      #pragma unroll
      for (int nt = 0; nt < 4; ++nt) {
        int col = w*64 + nt*16 + l15;
        #pragma unroll
        for (int i = 0; i < 4; ++i) {
          int row = mt*16 + g*4 + i;
          float vv = acc[mt][nt][i] + proj_b[col] + pe[row*256 + col];
          xres[mt][nt][i] = (f16)vv;
          B[row][col] = (f16)vv;
        }
      }
    }
  }
  __syncthreads();
  ln64v(B, B, t_nx_s, t_nx_b, w, lane);       // B: x -> xs (in place, row-local)
  __syncthreads();

  // ---- attention: wave w = head h; chunked to bound register pressure ----
  {
    const int h = w;
    // S^T accumulation, one 16-wide d-chunk of q^T/k^T at a time
    f32x4 sacc[4][4]; ZERO44(sacc);
    #pragma unroll
    for (int kd = 0; kd < 4; ++kd) {
      f32x4 qacc[4], kacc[4];
      #pragma unroll
      for (int nt = 0; nt < 4; ++nt) { qacc[nt] = zero4(); kacc[nt] = zero4(); }
      #pragma unroll
      for (int ks = 0; ks < 8; ++ks) {
        int kc = ks*32 + g*8;
        f16x8 xv[4];
        #pragma unroll
        for (int j = 0; j < 4; ++j) xv[j] = *(const f16x8*)&B[j*16 + l15][kc];
        f16x8 wq = *(const f16x8*)(wbuf + OFF_QW + (size_t)(h*64 + kd*16 + l15)*256 + kc);
        f16x8 wk = *(const f16x8*)(wbuf + OFF_KW + (size_t)(h*64 + kd*16 + l15)*256 + kc);
        #pragma unroll
        for (int nt = 0; nt < 4; ++nt) {
          qacc[nt] = MFMA32(wq, xv[nt], qacc[nt]);
          kacc[nt] = MFMA32(wk, xv[nt], kacc[nt]);
        }
      }
      f16x4 qf[4], kf[4];
      #pragma unroll
      for (int nt = 0; nt < 4; ++nt) {
        #pragma unroll
        for (int i = 0; i < 4; ++i) {
          qf[nt][i] = (f16)(qacc[nt][i] * 0.125f);
          kf[nt][i] = (f16)kacc[nt][i];
        }
      }
      #pragma unroll
      for (int ms = 0; ms < 4; ++ms) {
        #pragma unroll
        for (int nt = 0; nt < 4; ++nt)
          sacc[ms][nt] = MFMA16(kf[ms], qf[nt], sacc[ms][nt]);
      }
    }
    // softmax over s (rows of S^T): 16 in-lane + cross-g shfl
    f16x4 pf[4][4];
    #pragma unroll
    for (int nt = 0; nt < 4; ++nt) {
      float mx = -1e30f;
      #pragma unroll
      for (int ms = 0; ms < 4; ++ms) {
        #pragma unroll
        for (int i = 0; i < 4; ++i) mx = fmaxf(mx, sacc[ms][nt][i]);
      }
      mx = fmaxf(mx, __shfl_xor(mx, 16));
      mx = fmaxf(mx, __shfl_xor(mx, 32));
      float sm = 0.f;
      #pragma unroll
      for (int ms = 0; ms < 4; ++ms) {
        #pragma unroll
        for (int i = 0; i < 4; ++i) { float e = __expf(sacc[ms][nt][i] - mx); sacc[ms][nt][i] = e; sm += e; }
      }
      sm += __shfl_xor(sm, 16);
      sm += __shfl_xor(sm, 32);
      float r = 1.f / sm;
      #pragma unroll
      for (int ms = 0; ms < 4; ++ms) {
        #pragma unroll
        for (int i = 0; i < 4; ++i) pf[ms][nt][i] = (f16)(sacc[ms][nt][i] * r);
      }
    }
    // O^T = v^T @ P^T, one 16-row t-chunk of v at a time
    f32x4 oacc[4][4]; ZERO44(oacc);
    #pragma unroll
    for (int ks = 0; ks < 4; ++ks) {
      f32x4 vacc[4];
      #pragma unroll
      for (int nd = 0; nd < 4; ++nd) vacc[nd] = zero4();
      #pragma unroll
      for (int kk = 0; kk < 8; ++kk) {
        int kc = kk*32 + g*8;
        f16x8 xv = *(const f16x8*)&B[ks*16 + l15][kc];
        #pragma unroll
        for (int nd = 0; nd < 4; ++nd) {
          f16x8 wv = *(const f16x8*)(wbuf + OFF_VW + (size_t)(h*64 + nd*16 + l15)*256 + kc);
          vacc[nd] = MFMA32(xv, wv, vacc[nd]);
        }
      }
      f16x4 vf[4];
      #pragma unroll
      for (int nd = 0; nd < 4; ++nd) {
        #pragma unroll
        for (int i = 0; i < 4; ++i) vf[nd][i] = (f16)vacc[nd][i];
      }
      #pragma unroll
      for (int md = 0; md < 4; ++md) {
        #pragma unroll
        for (int nt = 0; nt < 4; ++nt)
          oacc[md][nt] = MFMA16(vf[md], pf[ks][nt], oacc[md][nt]);
      }
    }
    __syncthreads();   // all xs reads done before B is overwritten with O
    #pragma unroll
    for (int md = 0; md < 4; ++md) {
      #pragma unroll
      for (int nt = 0; nt < 4; ++nt) {
        int t = nt*16 + l15;
        f16x4 ov;
        #pragma unroll
        for (int i = 0; i < 4; ++i) ov[i] = (f16)oacc[md][nt][i];
        *(f16x4*)&B[t][h*64 + md*16 + g*4] = ov;
      }
    }
  }
  __syncthreads();

  // ---- xt = x + O @ t_ow + t_ob -> xres + B ----
  {
    f32x4 acc[4][4]; ZERO44(acc);
    gemm_ldsA<8,256>(B, wbuf + OFF_OW, acc, w, l15, g);
    __syncthreads();   // all waves done reading O
    #pragma unroll
    for (int mt = 0; mt < 4; ++mt) {
      #pragma unroll
      for (int nt = 0; nt < 4; ++nt) {
        int col = w*64 + nt*16 + l15;
        #pragma unroll
        for (int i = 0; i < 4; ++i) {
          int row = mt*16 + g*4 + i;
          float vv = (float)xres[mt][nt][i] + acc[mt][nt][i] + t_ob[col];
          xres[mt][nt][i] = (f16)vv;
          B[row][col] = (f16)vv;
        }
      }
    }
  }
  __syncthreads();
  ln64v(B, B, t_nf_s, t_nf_b, w, lane);       // B: xt -> y (in place)
  __syncthreads();

  // ---- FFN: zt = xt + relu(y@W1+b1)@W2 + b2 -> xres + B ----
  {
    f32x4 acc2[4][4]; ZERO44(acc2);
    for (int ch = 0; ch < 4; ++ch) {
      f32x4 ua[4];
      #pragma unroll
      for (int nt = 0; nt < 4; ++nt) ua[nt] = zero4();
      #pragma unroll
      for (int ks = 0; ks < 8; ++ks) {
        int kc = ks*32 + g*8;
        f16x8 av = *(const f16x8*)&B[w*16 + l15][kc];
        f16x8 bv[4];
        #pragma unroll
        for (int j = 0; j < 4; ++j) bv[j] = *(const f16x8*)(wbuf + OFF_F1 + (size_t)(ch*64 + j*16 + l15)*256 + kc);
        #pragma unroll
        for (int nt = 0; nt < 4; ++nt) ua[nt] = MFMA32(av, bv[nt], ua[nt]);
      }
      __syncthreads();
      #pragma unroll
      for (int nt = 0; nt < 4; ++nt) {
        int col = nt*16 + l15;
        #pragma unroll
        for (int i = 0; i < 4; ++i) {
          float v = ua[nt][i] + t_f1b[ch*64 + col];
          ub[w*16 + g*4 + i][col] = (f16)fmaxf(v, 0.f);
        }
      }
      __syncthreads();
      #pragma unroll
      for (int ks = 0; ks < 2; ++ks) {
        int kc = ks*32 + g*8;
        f16x8 av[4], bv[4];
        #pragma unroll
        for (int j = 0; j < 4; ++j) av[j] = *(const f16x8*)&ub[j*16 + l15][kc];
        #pragma unroll
        for (int j = 0; j < 4; ++j) bv[j] = *(const f16x8*)(wbuf + OFF_F2 + (size_t)(w*64 + j*16 + l15)*256 + ch*64 + kc);
        #pragma unroll
        for (int mt = 0; mt < 4; ++mt) {
          #pragma unroll
          for (int nt = 0; nt < 4; ++nt)
            acc2[mt][nt] = MFMA32(av[mt], bv[nt], acc2[mt][nt]);
        }
      }
    }
    // safe: all FFN1 reads of B precede the last chunk's post-ub-write barrier
    #pragma unroll
    for (int mt = 0; mt < 4; ++mt) {
      #pragma unroll
      for (int nt = 0; nt < 4; ++nt) {
        int col = w*64 + nt*16 + l15;
        #pragma unroll
        for (int i = 0; i < 4; ++i) {
          int row = mt*16 + g*4 + i;
          float vv = (float)xres[mt][nt][i] + acc2[mt][nt][i] + t_f2b[col];
          xres[mt][nt][i] = (f16)vv;
          B[row][col] = (f16)vv;
        }
      }
    }
  }
  __syncthreads();

  // ---- h = zt @ ta_w -> B ----
  {
    f32x4 acc[4][4]; ZERO44(acc);
    gemm_ldsA<8,256>(B, wbuf + OFF_TA, acc, w, l15, g);
    __syncthreads();   // all waves done reading zt
    #pragma unroll
    for (int mt = 0; mt < 4; ++mt) {
      #pragma unroll
      for (int nt = 0; nt < 4; ++nt) {
        int col = w*64 + nt*16 + l15;
        #pragma unroll
        for (int i = 0; i < 4; ++i) B[mt*16 + g*4 + i][col] = (f16)acc[mt][nt][i];
      }
    }
  }
  __syncthreads();

  // ---- temporal pooling: lam = softmax_t(h_t . h_63), z = sum lam_t * zt_t ----
  {
    int row = w*16 + (lane >> 2);
    int c0 = lane & 3;
    float dt = 0.f;
    #pragma unroll
    for (int j = 0; j < 8; ++j) {
      f16x8 va = *(const f16x8*)&B[row][j*32 + c0*8];
      f16x8 vb = *(const f16x8*)&B[63][j*32 + c0*8];
      #pragma unroll
      for (int e = 0; e < 8; ++e) dt += (float)va[e] * (float)vb[e];
    }
    dt += __shfl_xor(dt, 1); dt += __shfl_xor(dt, 2);
    if (c0 == 0) red[2 + row] = dt;
  }
  __syncthreads();
  if (tid < 64) {
    float v = red[2 + tid];
    float mx = v;
    #pragma unroll
    for (int off = 32; off >= 1; off >>= 1) mx = fmaxf(mx, __shfl_xor(mx, off));
    float e = __expf(v - mx);
    float sm = e;
    #pragma unroll
    for (int off = 32; off >= 1; off >>= 1) sm += __shfl_xor(sm, off);
    red[2 + tid] = e / sm;
  }
  __syncthreads();
  // z from the register-resident residual: reduce over rows held by g-groups
  {
    float zacc[4] = {0.f, 0.f, 0.f, 0.f};
    #pragma unroll
    for (int mt = 0; mt < 4; ++mt) {
      #pragma unroll
      for (int i = 0; i < 4; ++i) {
        float l = red[2 + mt*16 + g*4 + i];
        #pragma unroll
        for (int nt = 0; nt < 4; ++nt) zacc[nt] += l * (float)xres[mt][nt][i];
      }
    }
    #pragma unroll
    for (int nt = 0; nt < 4; ++nt) {
      zacc[nt] += __shfl_xor(zacc[nt], 16);
      zacc[nt] += __shfl_xor(zacc[nt], 32);
    }
    if (g == 0) {
      #pragma unroll
      for (int nt = 0; nt < 4; ++nt)
        zout[(size_t)n*256 + w*64 + nt*16 + l15] = zacc[nt];
    }
  }
}

// ---------------- K2: qk_in = [LN(z), LN(emb[id])] -> f16 ----------------
__global__ __launch_bounds__(256) void qkin_kernel(
    const float* __restrict__ z, const int* __restrict__ ids,
    const float* __restrict__ emb,
    const float* __restrict__ s_nx_s, const float* __restrict__ s_nx_b,
    const float* __restrict__ s_ni_s, const float* __restrict__ s_ni_b,
    f16* __restrict__ qk)
{
  int lane = threadIdx.x & 63;
  int w = threadIdx.x >> 6;
  int r = blockIdx.x*4 + w;
  const float* zr = z + (size_t)r*256;
  float v[4]; float s = 0.f, s2 = 0.f;
  #pragma unroll
  for (int j = 0; j < 4; ++j) { v[j] = zr[lane*4 + j]; s += v[j]; s2 += v[j]*v[j]; }
  #pragma unroll
  for (int off = 32; off >= 1; off >>= 1) { s += __shfl_xor(s, off); s2 += __shfl_xor(s2, off); }
  float mean = s*(1.f/256.f);
  float rstd = rsqrtf(s2*(1.f/256.f) - mean*mean + 1e-5f);
  f16* q = qk + (size_t)r*288;
  #pragma unroll
  for (int j = 0; j < 4; ++j) {
    int c = lane*4 + j;
    q[c] = (f16)((v[j] - mean)*rstd*s_nx_s[c] + s_nx_b[c]);
  }
  int id = ids[r];
  float e = (lane < 32) ? emb[id*32 + lane] : 0.f;
  float es = e, es2 = e*e;
  #pragma unroll
  for (int off = 16; off >= 1; off >>= 1) { es += __shfl_xor(es, off); es2 += __shfl_xor(es2, off); }
  if (lane < 32) {
    float m2 = es*(1.f/32.f);
    float rs2 = rsqrtf(es2*(1.f/32.f) - m2*m2 + 1e-5f);
    q[256 + lane] = (f16)((e - m2)*rs2*s_ni_s[lane] + s_ni_b[lane]);
  }
}

// ---------------- K3a: sq/sk = qk_in @ s_{q,k}w  (sq pre-scaled by 0.125) ------
__global__ __launch_bounds__(256) void sqk_kernel(const f16* __restrict__ qk,
    const f16* __restrict__ wbuf, f16* __restrict__ sq, f16* __restrict__ sk)
{
  const int tid = threadIdx.x, lane = tid & 63, w = tid >> 6, l15 = lane & 15, g = lane >> 4;
  const int isk = blockIdx.y;
  const f16* W = wbuf + (isk ? OFF_SKW : OFF_SQW);
  f16* out = isk ? sk : sq;
  const float scale = isk ? 1.f : 0.125f;
  const int r0 = blockIdx.x*64;
  f32x4 acc[4][4]; ZERO44(acc);
  #pragma unroll
  for (int ks = 0; ks < 9; ++ks) {
    int kc = ks*32 + g*8;
    f16x8 av[4], bv[4];
    #pragma unroll
    for (int j = 0; j < 4; ++j) av[j] = *(const f16x8*)(qk + (size_t)(r0 + j*16 + l15)*288 + kc);
    #pragma unroll
    for (int j = 0; j < 4; ++j) bv[j] = *(const f16x8*)(W + (size_t)(w*64 + j*16 + l15)*288 + kc);
    #pragma unroll
    for (int mt = 0; mt < 4; ++mt) {
      #pragma unroll
      for (int nt = 0; nt < 4; ++nt) acc[mt][nt] = MFMA32(av[mt], bv[nt], acc[mt][nt]);
    }
  }
  #pragma unroll
  for (int mt = 0; mt < 4; ++mt) {
    #pragma unroll
    for (int nt = 0; nt < 4; ++nt) {
      int col = w*64 + nt*16 + l15;
      #pragma unroll
      for (int i = 0; i < 4; ++i)
        out[(size_t)(r0 + mt*16 + g*4 + i)*256 + col] = (f16)(acc[mt][nt][i]*scale);
    }
  }
}

// ---------------- K3b: svT[d][key] = (zs @ s_vw)^T via transpose-GEMM ----------
__global__ __launch_bounds__(256) void svt_kernel(const f16* __restrict__ qk,
    const f16* __restrict__ wbuf, f16* __restrict__ svT)
{
  const int tid = threadIdx.x, lane = tid & 63, w = tid >> 6, l15 = lane & 15, g = lane >> 4;
  const int k0 = blockIdx.x*64;
  f32x4 acc[4][4]; ZERO44(acc);
  #pragma unroll
  for (int ks = 0; ks < 8; ++ks) {
    int kc = ks*32 + g*8;
    f16x8 av[4], bv[4];
    #pragma unroll
    for (int j = 0; j < 4; ++j) av[j] = *(const f16x8*)(wbuf + OFF_SVW + (size_t)(w*64 + j*16 + l15)*256 + kc);
    #pragma unroll
    for (int j = 0; j < 4; ++j) bv[j] = *(const f16x8*)(qk + (size_t)(k0 + j*16 + l15)*288 + kc);
    #pragma unroll
    for (int md = 0; md < 4; ++md) {
      #pragma unroll
      for (int nk = 0; nk < 4; ++nk) acc[md][nk] = MFMA32(av[md], bv[nk], acc[md][nk]);
    }
  }
  #pragma unroll
  for (int md = 0; md < 4; ++md) {
    #pragma unroll
    for (int nk = 0; nk < 4; ++nk) {
      int key = k0 + nk*16 + l15;
      #pragma unroll
      for (int i = 0; i < 4; ++i)
        svT[(size_t)(w*64 + md*16 + g*4 + i)*4096 + key] = (f16)acc[md][nk][i];
    }
  }
}

// ---------------- K4: flash cross-sectional attention (4096 keys) --------------
__global__ __launch_bounds__(256) void xattn_kernel(const f16* __restrict__ sq,
    const f16* __restrict__ sk, const f16* __restrict__ svT, f16* __restrict__ so)
{
  const int lane = threadIdx.x & 63, w = threadIdx.x >> 6, l15 = lane & 15, g = lane >> 4;
  const int h = blockIdx.y;
  const int q0 = blockIdx.x*64 + w*16;
  const f16* qp = sq + (size_t)q0*256 + h*64;
  f16x8 qf0 = *(const f16x8*)(qp + (size_t)l15*256 + g*8);
  f16x8 qf1 = *(const f16x8*)(qp + (size_t)l15*256 + 32 + g*8);
  f32x4 oacc[4];
  #pragma unroll
  for (int md = 0; md < 4; ++md) oacc[md] = zero4();
  float mrun = -1e30f, lrun = 0.f;
  for (int kt = 0; kt < 64; ++kt) {
    const f16* kp = sk + (size_t)kt*64*256 + h*64;
    f32x4 sacc[4];
    #pragma unroll
    for (int mt = 0; mt < 4; ++mt) sacc[mt] = zero4();
    #pragma unroll
    for (int mt = 0; mt < 4; ++mt) {
      f16x8 k0f = *(const f16x8*)(kp + (size_t)(mt*16 + l15)*256 + g*8);
      f16x8 k1f = *(const f16x8*)(kp + (size_t)(mt*16 + l15)*256 + 32 + g*8);
      sacc[mt] = MFMA32(k0f, qf0, sacc[mt]);
      sacc[mt] = MFMA32(k1f, qf1, sacc[mt]);
    }
    float tmax = -1e30f;
    #pragma unroll
    for (int mt = 0; mt < 4; ++mt) {
      #pragma unroll
      for (int i = 0; i < 4; ++i) tmax = fmaxf(tmax, sacc[mt][i]);
    }
    tmax = fmaxf(tmax, __shfl_xor(tmax, 16));
    tmax = fmaxf(tmax, __shfl_xor(tmax, 32));
    float mnew = fmaxf(mrun, tmax);
    float corr = __expf(mrun - mnew);
    float ts = 0.f;
    #pragma unroll
    for (int mt = 0; mt < 4; ++mt) {
      #pragma unroll
      for (int i = 0; i < 4; ++i) { float e = __expf(sacc[mt][i] - mnew); sacc[mt][i] = e; ts += e; }
    }
    ts += __shfl_xor(ts, 16);
    ts += __shfl_xor(ts, 32);
    lrun = lrun*corr + ts;
    mrun = mnew;
    f16x4 pf[4];
    #pragma unroll
    for (int mt = 0; mt < 4; ++mt) {
      #pragma unroll
      for (int i = 0; i < 4; ++i) pf[mt][i] = (f16)sacc[mt][i];
    }
    #pragma unroll
    for (int md = 0; md < 4; ++md) {
      #pragma unroll
      for (int i = 0; i < 4; ++i) oacc[md][i] *= corr;
    }
    const f16* vp = svT + (size_t)h*64*4096 + kt*64;
    #pragma unroll
    for (int ks = 0; ks < 4; ++ks) {
      #pragma unroll
      for (int md = 0; md < 4; ++md) {
        f16x4 vf = *(const f16x4*)(vp + (size_t)(md*16 + l15)*4096 + ks*16 + g*4);
        oacc[md] = MFMA16(vf, pf[ks], oacc[md]);
      }
    }
  }
  float rinv = 1.f / lrun;
  #pragma unroll
  for (int md = 0; md < 4; ++md) {
    f16x4 ov;
    #pragma unroll
    for (int i = 0; i < 4; ++i) ov[i] = (f16)(oacc[md][i]*rinv);
    *(f16x4*)(so + (size_t)(q0 + l15)*256 + h*64 + md*16 + g*4) = ov;
  }
}

// ---------------- K5: zt = z + so@s_ow+b -> LN -> FFN -> dec -------------------
__global__ __launch_bounds__(256, 2) void final_kernel(
    const f16* __restrict__ so, const float* __restrict__ z,
    const f16* __restrict__ wbuf,
    const float* __restrict__ s_ob,
    const float* __restrict__ s_nf_s, const float* __restrict__ s_nf_b,
    const float* __restrict__ s_f1b, const float* __restrict__ s_f2b,
    const float* __restrict__ dec_w, const float* __restrict__ dec_b,
    float* __restrict__ out)
{
  __shared__ __align__(16) f16 zb[64][264];
  __shared__ __align__(16) f16 yb[64][264];
  __shared__ __align__(16) f16 ub[64][72];
  const int tid = threadIdx.x, lane = tid & 63, w = tid >> 6, l15 = lane & 15, g = lane >> 4;
  const int r0 = blockIdx.x*64;
  {
    f32x4 acc[4][4]; ZERO44(acc);
    #pragma unroll
    for (int ks = 0; ks < 8; ++ks) {
      int kc = ks*32 + g*8;
      f16x8 av[4], bv[4];
      #pragma unroll
      for (int j = 0; j < 4; ++j) av[j] = *(const f16x8*)(so + (size_t)(r0 + j*16 + l15)*256 + kc);
      #pragma unroll
      for (int j = 0; j < 4; ++j) bv[j] = *(const f16x8*)(wbuf + OFF_SOW + (size_t)(w*64 + j*16 + l15)*256 + kc);
      #pragma unroll
      for (int mt = 0; mt < 4; ++mt) {
        #pragma unroll
        for (int nt = 0; nt < 4; ++nt) acc[mt][nt] = MFMA32(av[mt], bv[nt], acc[mt][nt]);
      }
    }
    #pragma unroll
    for (int mt = 0; mt < 4; ++mt) {
      #pragma unroll
      for (int nt = 0; nt < 4; ++nt) {
        int col = w*64 + nt*16 + l15;
        #pragma unroll
        for (int i = 0; i < 4; ++i) {
          int row = mt*16 + g*4 + i;
          zb[row][col] = (f16)(z[(size_t)(r0 + row)*256 + col] + acc[mt][nt][i] + s_ob[col]);
        }
      }
    }
  }
  __syncthreads();
  ln64v(zb, yb, s_nf_s, s_nf_b, w, lane);
  __syncthreads();
  ffn_block(zb, yb, ub, wbuf + OFF_SF1, wbuf + OFF_SF2, s_f1b, s_f2b, w, l15, g);
  __syncthreads();
  {
    int row = w*16 + (lane >> 2), c0 = lane & 3;
    float dt = 0.f;
    #pragma unroll
    for (int j = 0; j < 8; ++j) {
      f16x8 va = *(const f16x8*)&zb[row][j*32 + c0*8];
      #pragma unroll
      for (int e = 0; e < 8; ++e) dt += (float)va[e]*dec_w[j*32 + c0*8 + e];
    }
    dt += __shfl_xor(dt, 1); dt += __shfl_xor(dt, 2);
    if (c0 == 0) out[r0 + row] = dt + dec_b[0];
  }
}

// ---------------- launch ----------------
extern "C" void kernel_launch(void* const* d_in, const int* in_sizes, int n_in,
                              void* d_out, int out_size, void* d_ws, size_t ws_size,
                              hipStream_t stream)
{
  const int*   ids    = (const int*)  d_in[0];
  const float* stock  = (const float*)d_in[1];
  const float* market = (const float*)d_in[2];
  const float* emb    = (const float*)d_in[3];
  const float* gate_w = (const float*)d_in[4];
  const float* gate_b = (const float*)d_in[5];

  char* ws = (char*)d_ws;
  f16*   wbuf = (f16*)ws;
  float* pe   = (float*)(ws + PE_B);
  float* zbuf = (float*)(ws + Z_B);
  f16*   qk   = (f16*)(ws + QK_B);
  f16*   sq   = (f16*)(ws + SQ_B);
  f16*   sk   = (f16*)(ws + SK_B);
  f16*   svT  = (f16*)(ws + SVT_B);
  f16*   so   = (f16*)(ws + SO_B);

  PrepArgs pa;
  const int srcIdx[14] = {6,8,9,10,11,17,19,36,21,22,23,24,32,34};
  const int Ks[14]   = {158,256,256,256,256,256,256,256,288,288,256,256,256,256};
  const int Kps[14]  = {160,256,256,256,256,256,256,256,288,288,256,256,256,256};
  const int offs[14] = {(int)OFF_PROJ,(int)OFF_QW,(int)OFF_KW,(int)OFF_VW,(int)OFF_OW,
                        (int)OFF_F1,(int)OFF_F2,(int)OFF_TA,(int)OFF_SQW,(int)OFF_SKW,
                        (int)OFF_SVW,(int)OFF_SOW,(int)OFF_SF1,(int)OFF_SF2};
  for (int i = 0; i < 14; ++i) {
    pa.src[i] = (const float*)d_in[srcIdx[i]];
    pa.K[i] = Ks[i]; pa.Kp[i] = Kps[i]; pa.off[i] = offs[i];
  }

  prep_kernel<<<dim3(64,15), dim3(256), 0, stream>>>(pa, wbuf, pe);
  temporal_kernel<<<dim3(4096), dim3(256), 0, stream>>>(
      stock, market, gate_w, gate_b,
      (const float*)d_in[7],  (const float*)d_in[12],
      (const float*)d_in[13], (const float*)d_in[14],
      (const float*)d_in[15], (const float*)d_in[16],
      (const float*)d_in[18], (const float*)d_in[20],
      wbuf, pe, zbuf);
  qkin_kernel<<<dim3(1024), dim3(256), 0, stream>>>(
      zbuf, ids, emb,
      (const float*)d_in[26], (const float*)d_in[27],
      (const float*)d_in[28], (const float*)d_in[29], qk);
  sqk_kernel<<<dim3(64,2), dim3(256), 0, stream>>>(qk, wbuf, sq, sk);
  svt_kernel<<<dim3(64), dim3(256), 0, stream>>>(qk, wbuf, svT);
  xattn_kernel<<<dim3(64,4), dim3(256), 0, stream>>>(sq, sk, svT, so);
  final_kernel<<<dim3(64), dim3(256), 0, stream>>>(
      so, zbuf, wbuf,
      (const float*)d_in[25], (const float*)d_in[30], (const float*)d_in[31],
      (const float*)d_in[33], (const float*)d_in[35],
      (const float*)d_in[37], (const float*)d_in[38], (float*)d_out);
}

// Round 4
// 1091.271 us; speedup vs baseline: 2.0940x; 2.0940x over previous
//
#include <hip/hip_runtime.h>

typedef _Float16 f16;
typedef _Float16 f16x8 __attribute__((ext_vector_type(8)));
typedef _Float16 f16x4 __attribute__((ext_vector_type(4)));
typedef float    f32x4 __attribute__((ext_vector_type(4)));

#define MFMA32(a,b,c) __builtin_amdgcn_mfma_f32_16x16x32_f16((a),(b),(c),0,0,0)
#define MFMA16(a,b,c) __builtin_amdgcn_mfma_f32_16x16x16f16((a),(b),(c),0,0,0)

__device__ __forceinline__ f32x4 zero4() { f32x4 v = {0.f,0.f,0.f,0.f}; return v; }
#define ZERO44(A) { _Pragma("unroll") for (int z1=0;z1<4;++z1){ _Pragma("unroll") for (int z2=0;z2<4;++z2) A[z1][z2] = zero4(); } }

// ---- workspace layout ----
constexpr size_t OFF_PROJ = 0;        // [256][160] (K 158 padded to 160)
constexpr size_t OFF_QW  = 40960;     // [256][256]
constexpr size_t OFF_KW  = 106496;
constexpr size_t OFF_VW  = 172032;
constexpr size_t OFF_OW  = 237568;
constexpr size_t OFF_F1  = 303104;
constexpr size_t OFF_F2  = 368640;
constexpr size_t OFF_TA  = 434176;
constexpr size_t OFF_SQW = 499712;    // [256][288]
constexpr size_t OFF_SKW = 573440;    // [256][288]
constexpr size_t OFF_SVW = 647168;    // [256][256]
constexpr size_t OFF_SOW = 712704;
constexpr size_t OFF_SF1 = 778240;
constexpr size_t OFF_SF2 = 843776;
constexpr size_t W_ELEMS = 909312;
constexpr size_t PE_B  = W_ELEMS*2;             // pos-enc 64*256 f32
constexpr size_t Z_B   = PE_B  + 64*256*4;      // z    4096*256 f32
constexpr size_t QK_B  = Z_B   + 4096ull*256*4; // qk_in 4096*288 f16
constexpr size_t SQ_B  = QK_B  + 4096ull*288*2; // sq   4096*256 f16 (pre-scaled 0.125)
constexpr size_t SK_B  = SQ_B  + 4096ull*256*2; // sk
constexpr size_t SVT_B = SK_B  + 4096ull*256*2; // svT [256][4096] f16
constexpr size_t SO_B  = SVT_B + 4096ull*256*2; // so   4096*256 f16

// ---------------- prep: transpose weights to f16 WT, build pos-enc -------------
struct PrepArgs {
  const float* src[14];
  int K[14]; int Kp[14]; int off[14];
};

__global__ void prep_kernel(PrepArgs a, f16* __restrict__ wbuf, float* __restrict__ pe) {
  int wsel = blockIdx.y;
  int tid = threadIdx.x;
  if (wsel < 14) {
    const float* S = a.src[wsel];
    int K = a.K[wsel], Kp = a.Kp[wsel];
    f16* D = wbuf + a.off[wsel];
    int n = blockIdx.x*4 + (tid & 3);
    for (int k = (tid >> 2); k < Kp; k += 64) {
      float v = (k < K) ? S[(size_t)k*256 + n] : 0.f;
      D[(size_t)n*Kp + k] = (f16)v;
    }
  } else {
    int idx = blockIdx.x*256 + tid;       // gridDim.x = 64 -> 16384 = 64*256
    int t = idx >> 8, d = idx & 255, i = d >> 1;
    float div = expf((float)(2*i) * (-9.210340371976184f/256.f));
    float ang = (float)t * div;
    pe[idx] = (d & 1) ? cosf(ang) : sinf(ang);
  }
}

// ---------------- shared helpers ----------------
// vectorized LN over 64 rows x 256 cols (f16 LDS -> f16 LDS, src may == dst)
__device__ __forceinline__ void ln64v(f16 (*src)[264], f16 (*dst)[264],
    const float* __restrict__ sc, const float* __restrict__ bi, int w, int lane) {
  int row = w*16 + (lane >> 2);
  int c0 = lane & 3;               // lane covers cols j*32 + c0*8 .. +8
  f16x8 v[8];
  float s = 0.f, s2 = 0.f;
  #pragma unroll
  for (int j = 0; j < 8; ++j) {
    v[j] = *(const f16x8*)&src[row][j*32 + c0*8];
    #pragma unroll
    for (int e = 0; e < 8; ++e) { float f = (float)v[j][e]; s += f; s2 += f*f; }
  }
  s  += __shfl_xor(s, 1);  s  += __shfl_xor(s, 2);
  s2 += __shfl_xor(s2, 1); s2 += __shfl_xor(s2, 2);
  float mean = s * (1.f/256.f);
  float rstd = rsqrtf(s2 * (1.f/256.f) - mean*mean + 1e-5f);
  #pragma unroll
  for (int j = 0; j < 8; ++j) {
    int c = j*32 + c0*8;
    f16x8 o;
    #pragma unroll
    for (int e = 0; e < 8; ++e)
      o[e] = (f16)(((float)v[j][e] - mean) * rstd * sc[c+e] + bi[c+e]);
    *(f16x8*)&dst[row][c] = o;
  }
}

// C[64x64chunk] += A(LDS rows t, k contig) @ B(WT global), wave w owns cols [64w,64w+64)
// unroll 2: bound load-hoisting so staging regs stay ~2 iterations deep
template<int KSTEPS, int LDB>
__device__ __forceinline__ void gemm_ldsA(f16 (*A)[264], const f16* __restrict__ B,
                                          f32x4 (&acc)[4][4], int w, int l15, int g) {
  #pragma unroll 2
  for (int ks = 0; ks < KSTEPS; ++ks) {
    int kc = ks*32 + g*8;
    f16x8 av[4], bv[4];
    #pragma unroll
    for (int j = 0; j < 4; ++j) av[j] = *(const f16x8*)&A[j*16 + l15][kc];
    #pragma unroll
    for (int j = 0; j < 4; ++j) bv[j] = *(const f16x8*)(B + (size_t)(w*64 + j*16 + l15)*LDB + kc);
    #pragma unroll
    for (int mt = 0; mt < 4; ++mt) {
      #pragma unroll
      for (int nt = 0; nt < 4; ++nt)
        acc[mt][nt] = MFMA32(av[mt], bv[nt], acc[mt][nt]);
    }
  }
}

// FFN with LDS residual (used by final_kernel only)
__device__ __forceinline__ void ffn_block(f16 (*res)[264], f16 (*y)[264], f16 (*u)[72],
    const f16* __restrict__ W1, const f16* __restrict__ W2,
    const float* __restrict__ b1, const float* __restrict__ b2,
    int w, int l15, int g) {
  f32x4 acc2[4][4]; ZERO44(acc2);
  for (int ch = 0; ch < 4; ++ch) {
    f32x4 ua[4];
    #pragma unroll
    for (int nt = 0; nt < 4; ++nt) ua[nt] = zero4();
    #pragma unroll 2
    for (int ks = 0; ks < 8; ++ks) {
      int kc = ks*32 + g*8;
      f16x8 av = *(const f16x8*)&y[w*16 + l15][kc];
      f16x8 bv[4];
      #pragma unroll
      for (int j = 0; j < 4; ++j) bv[j] = *(const f16x8*)(W1 + (size_t)(ch*64 + j*16 + l15)*256 + kc);
      #pragma unroll
      for (int nt = 0; nt < 4; ++nt) ua[nt] = MFMA32(av, bv[nt], ua[nt]);
    }
    __syncthreads();
    #pragma unroll
    for (int nt = 0; nt < 4; ++nt) {
      int col = nt*16 + l15;
      #pragma unroll
      for (int i = 0; i < 4; ++i) {
        float v = ua[nt][i] + b1[ch*64 + col];
        u[w*16 + g*4 + i][col] = (f16)fmaxf(v, 0.f);
      }
    }
    __syncthreads();
    #pragma unroll
    for (int ks = 0; ks < 2; ++ks) {
      int kc = ks*32 + g*8;
      f16x8 av[4], bv[4];
      #pragma unroll
      for (int j = 0; j < 4; ++j) av[j] = *(const f16x8*)&u[j*16 + l15][kc];
      #pragma unroll
      for (int j = 0; j < 4; ++j) bv[j] = *(const f16x8*)(W2 + (size_t)(w*64 + j*16 + l15)*256 + ch*64 + kc);
      #pragma unroll
      for (int mt = 0; mt < 4; ++mt) {
        #pragma unroll
        for (int nt = 0; nt < 4; ++nt)
          acc2[mt][nt] = MFMA32(av[mt], bv[nt], acc2[mt][nt]);
      }
    }
  }
  #pragma unroll
  for (int mt = 0; mt < 4; ++mt) {
    #pragma unroll
    for (int nt = 0; nt < 4; ++nt) {
      int col = w*64 + nt*16 + l15;
      #pragma unroll
      for (int i = 0; i < 4; ++i) {
        int row = mt*16 + g*4 + i;
        float v = (float)res[row][col] + acc2[mt][nt][i] + b2[col];
        res[row][col] = (f16)v;
      }
    }
  }
}

// ---------------- K1: fused temporal transformer, one block per stock ----------
// Single LDS buffer; residual in registers (f16 C-frag layout); attention is
// chunked (kd-split QK, ks-split PV); budget 256 regs (2 waves/EU min).
__global__ __launch_bounds__(256, 2) void temporal_kernel(
    const float* __restrict__ stock, const float* __restrict__ market,
    const float* __restrict__ gate_w, const float* __restrict__ gate_b,
    const float* __restrict__ proj_b, const float* __restrict__ t_ob,
    const float* __restrict__ t_nx_s, const float* __restrict__ t_nx_b,
    const float* __restrict__ t_nf_s, const float* __restrict__ t_nf_b,
    const float* __restrict__ t_f1b, const float* __restrict__ t_f2b,
    const f16* __restrict__ wbuf, const float* __restrict__ pe,
    float* __restrict__ zout)
{
  __shared__ __align__(16) f16 B[64][264];    // gated-feat / x / xs / O / y / zt / h
  __shared__ __align__(16) f16 ub[64][72];    // FFN hidden chunk
  __shared__ float gatev[160];
  __shared__ float mkt[64];
  __shared__ float red[66];

  const int tid = threadIdx.x;
  const int lane = tid & 63;
  const int w = tid >> 6;
  const int l15 = lane & 15;
  const int g = lane >> 4;
  const int n = blockIdx.x;

  f16x4 xres[4][4];   // residual: [row=mt*16+g*4+i][col=w*64+nt*16+l15]

  // ---- market gate: 158 * softmax(mkt @ gate_w + gate_b) ----
  if (tid < 64) mkt[tid] = market[(size_t)n*4096 + 63*64 + tid];
  __syncthreads();
  float logit = 0.f;
  if (tid < 158) {
    float acc = gate_b[tid];
    for (int m = 0; m < 64; ++m) acc += mkt[m] * gate_w[m*158 + tid];
    logit = acc;
  }
  if (tid < 160) gatev[tid] = (tid < 158) ? logit : -1e30f;
  __syncthreads();
  if (w == 0) {
    float v = fmaxf(gatev[lane], gatev[lane + 64]);
    if (lane < 32) v = fmaxf(v, gatev[lane + 128]);
    #pragma unroll
    for (int off = 32; off >= 1; off >>= 1) v = fmaxf(v, __shfl_xor(v, off));
    if (lane == 0) red[0] = v;
  }
  __syncthreads();
  float gmax = red[0];
  float ev = (tid < 158) ? __expf(logit - gmax) : 0.f;
  if (tid < 160) gatev[tid] = ev;
  __syncthreads();
  if (w == 0) {
    float v = gatev[lane] + gatev[lane + 64] + ((lane < 32) ? gatev[lane + 128] : 0.f);
    #pragma unroll
    for (int off = 32; off >= 1; off >>= 1) v += __shfl_xor(v, off);
    if (lane == 0) red[1] = v;
  }
  __syncthreads();
  const float grs = 158.f / red[1];

  // ---- gated stock features -> B, K padded to 160 ----
  for (int idx = tid; idx < 64*158; idx += 256) {
    int t = idx / 158, f = idx - t*158;
    B[t][f] = (f16)(stock[(size_t)n*(64*158) + idx] * (gatev[f] * grs));
  }
  if (tid < 128) B[tid >> 1][158 + (tid & 1)] = (f16)0.f;
  __syncthreads();

  // ---- x = gated @ proj_w + proj_b + pe -> xres + B ----
  {
    f32x4 acc[4][4]; ZERO44(acc);
    gemm_ldsA<5,160>(B, wbuf + OFF_PROJ, acc, w, l15, g);
    __syncthreads();   // all waves done reading gated features
    #pragma unroll
    for (int mt = 0; mt < 4; ++mt) {
      #pragma unroll
      for (int nt = 0; nt < 4; ++nt) {
        int col = w*64 + nt*16 + l15;
        #pragma unroll
        for (int i = 0; i < 4; ++i) {
          int row = mt*16 + g*4 + i;
          float vv = acc[mt][nt][i] + proj_b[col] + pe[row*256 + col];
          xres[mt][nt][i] = (f16)vv;
          B[row][col] = (f16)vv;
        }
      }
    }
  }
  __syncthreads();
  ln64v(B, B, t_nx_s, t_nx_b, w, lane);       // B: x -> xs (in place, row-local)
  __syncthreads();

  // ---- attention: wave w = head h; chunked to bound register pressure ----
  {
    const int h = w;
    // S^T accumulation, one 16-wide d-chunk of q^T/k^T at a time
    f32x4 sacc[4][4]; ZERO44(sacc);
    #pragma unroll
    for (int kd = 0; kd < 4; ++kd) {
      f32x4 qacc[4], kacc[4];
      #pragma unroll
      for (int nt = 0; nt < 4; ++nt) { qacc[nt] = zero4(); kacc[nt] = zero4(); }
      #pragma unroll 2
      for (int ks = 0; ks < 8; ++ks) {
        int kc = ks*32 + g*8;
        f16x8 xv[4];
        #pragma unroll
        for (int j = 0; j < 4; ++j) xv[j] = *(const f16x8*)&B[j*16 + l15][kc];
        f16x8 wq = *(const f16x8*)(wbuf + OFF_QW + (size_t)(h*64 + kd*16 + l15)*256 + kc);
        f16x8 wk = *(const f16x8*)(wbuf + OFF_KW + (size_t)(h*64 + kd*16 + l15)*256 + kc);
        #pragma unroll
        for (int nt = 0; nt < 4; ++nt) {
          qacc[nt] = MFMA32(wq, xv[nt], qacc[nt]);
          kacc[nt] = MFMA32(wk, xv[nt], kacc[nt]);
        }
      }
      f16x4 qf[4], kf[4];
      #pragma unroll
      for (int nt = 0; nt < 4; ++nt) {
        #pragma unroll
        for (int i = 0; i < 4; ++i) {
          qf[nt][i] = (f16)(qacc[nt][i] * 0.125f);
          kf[nt][i] = (f16)kacc[nt][i];
        }
      }
      #pragma unroll
      for (int ms = 0; ms < 4; ++ms) {
        #pragma unroll
        for (int nt = 0; nt < 4; ++nt)
          sacc[ms][nt] = MFMA16(kf[ms], qf[nt], sacc[ms][nt]);
      }
    }
    // softmax over s (rows of S^T): 16 in-lane + cross-g shfl
    f16x4 pf[4][4];
    #pragma unroll
    for (int nt = 0; nt < 4; ++nt) {
      float mx = -1e30f;
      #pragma unroll
      for (int ms = 0; ms < 4; ++ms) {
        #pragma unroll
        for (int i = 0; i < 4; ++i) mx = fmaxf(mx, sacc[ms][nt][i]);
      }
      mx = fmaxf(mx, __shfl_xor(mx, 16));
      mx = fmaxf(mx, __shfl_xor(mx, 32));
      float sm = 0.f;
      #pragma unroll
      for (int ms = 0; ms < 4; ++ms) {
        #pragma unroll
        for (int i = 0; i < 4; ++i) { float e = __expf(sacc[ms][nt][i] - mx); sacc[ms][nt][i] = e; sm += e; }
      }
      sm += __shfl_xor(sm, 16);
      sm += __shfl_xor(sm, 32);
      float r = 1.f / sm;
      #pragma unroll
      for (int ms = 0; ms < 4; ++ms) {
        #pragma unroll
        for (int i = 0; i < 4; ++i) pf[ms][nt][i] = (f16)(sacc[ms][nt][i] * r);
      }
    }
    // O^T = v^T @ P^T, one 16-row t-chunk of v at a time
    f32x4 oacc[4][4]; ZERO44(oacc);
    #pragma unroll
    for (int ks = 0; ks < 4; ++ks) {
      f32x4 vacc[4];
      #pragma unroll
      for (int nd = 0; nd < 4; ++nd) vacc[nd] = zero4();
      #pragma unroll 2
      for (int kk = 0; kk < 8; ++kk) {
        int kc = kk*32 + g*8;
        f16x8 xv = *(const f16x8*)&B[ks*16 + l15][kc];
        #pragma unroll
        for (int nd = 0; nd < 4; ++nd) {
          f16x8 wv = *(const f16x8*)(wbuf + OFF_VW + (size_t)(h*64 + nd*16 + l15)*256 + kc);
          vacc[nd] = MFMA32(xv, wv, vacc[nd]);
        }
      }
      f16x4 vf[4];
      #pragma unroll
      for (int nd = 0; nd < 4; ++nd) {
        #pragma unroll
        for (int i = 0; i < 4; ++i) vf[nd][i] = (f16)vacc[nd][i];
      }
      #pragma unroll
      for (int md = 0; md < 4; ++md) {
        #pragma unroll
        for (int nt = 0; nt < 4; ++nt)
          oacc[md][nt] = MFMA16(vf[md], pf[ks][nt], oacc[md][nt]);
      }
    }
    __syncthreads();   // all xs reads done before B is overwritten with O
    #pragma unroll
    for (int md = 0; md < 4; ++md) {
      #pragma unroll
      for (int nt = 0; nt < 4; ++nt) {
        int t = nt*16 + l15;
        f16x4 ov;
        #pragma unroll
        for (int i = 0; i < 4; ++i) ov[i] = (f16)oacc[md][nt][i];
        *(f16x4*)&B[t][h*64 + md*16 + g*4] = ov;
      }
    }
  }
  __syncthreads();

  // ---- xt = x + O @ t_ow + t_ob -> xres + B ----
  {
    f32x4 acc[4][4]; ZERO44(acc);
    gemm_ldsA<8,256>(B, wbuf + OFF_OW, acc, w, l15, g);
    __syncthreads();   // all waves done reading O
    #pragma unroll
    for (int mt = 0; mt < 4; ++mt) {
      #pragma unroll
      for (int nt = 0; nt < 4; ++nt) {
        int col = w*64 + nt*16 + l15;
        #pragma unroll
        for (int i = 0; i < 4; ++i) {
          int row = mt*16 + g*4 + i;
          float vv = (float)xres[mt][nt][i] + acc[mt][nt][i] + t_ob[col];
          xres[mt][nt][i] = (f16)vv;
          B[row][col] = (f16)vv;
        }
      }
    }
  }
  __syncthreads();
  ln64v(B, B, t_nf_s, t_nf_b, w, lane);       // B: xt -> y (in place)
  __syncthreads();

  // ---- FFN: zt = xt + relu(y@W1+b1)@W2 + b2 -> xres + B ----
  {
    f32x4 acc2[4][4]; ZERO44(acc2);
    for (int ch = 0; ch < 4; ++ch) {
      f32x4 ua[4];
      #pragma unroll
      for (int nt = 0; nt < 4; ++nt) ua[nt] = zero4();
      #pragma unroll 2
      for (int ks = 0; ks < 8; ++ks) {
        int kc = ks*32 + g*8;
        f16x8 av = *(const f16x8*)&B[w*16 + l15][kc];
        f16x8 bv[4];
        #pragma unroll
        for (int j = 0; j < 4; ++j) bv[j] = *(const f16x8*)(wbuf + OFF_F1 + (size_t)(ch*64 + j*16 + l15)*256 + kc);
        #pragma unroll
        for (int nt = 0; nt < 4; ++nt) ua[nt] = MFMA32(av, bv[nt], ua[nt]);
      }
      __syncthreads();
      #pragma unroll
      for (int nt = 0; nt < 4; ++nt) {
        int col = nt*16 + l15;
        #pragma unroll
        for (int i = 0; i < 4; ++i) {
          float v = ua[nt][i] + t_f1b[ch*64 + col];
          ub[w*16 + g*4 + i][col] = (f16)fmaxf(v, 0.f);
        }
      }
      __syncthreads();
      #pragma unroll
      for (int ks = 0; ks < 2; ++ks) {
        int kc = ks*32 + g*8;
        f16x8 av[4], bv[4];
        #pragma unroll
        for (int j = 0; j < 4; ++j) av[j] = *(const f16x8*)&ub[j*16 + l15][kc];
        #pragma unroll
        for (int j = 0; j < 4; ++j) bv[j] = *(const f16x8*)(wbuf + OFF_F2 + (size_t)(w*64 + j*16 + l15)*256 + ch*64 + kc);
        #pragma unroll
        for (int mt = 0; mt < 4; ++mt) {
          #pragma unroll
          for (int nt = 0; nt < 4; ++nt)
            acc2[mt][nt] = MFMA32(av[mt], bv[nt], acc2[mt][nt]);
        }
      }
    }
    // safe: all FFN1 reads of B precede the last chunk's post-ub-write barrier
    #pragma unroll
    for (int mt = 0; mt < 4; ++mt) {
      #pragma unroll
      for (int nt = 0; nt < 4; ++nt) {
        int col = w*64 + nt*16 + l15;
        #pragma unroll
        for (int i = 0; i < 4; ++i) {
          int row = mt*16 + g*4 + i;
          float vv = (float)xres[mt][nt][i] + acc2[mt][nt][i] + t_f2b[col];
          xres[mt][nt][i] = (f16)vv;
          B[row][col] = (f16)vv;
        }
      }
    }
  }
  __syncthreads();

  // ---- h = zt @ ta_w -> B ----
  {
    f32x4 acc[4][4]; ZERO44(acc);
    gemm_ldsA<8,256>(B, wbuf + OFF_TA, acc, w, l15, g);
    __syncthreads();   // all waves done reading zt
    #pragma unroll
    for (int mt = 0; mt < 4; ++mt) {
      #pragma unroll
      for (int nt = 0; nt < 4; ++nt) {
        int col = w*64 + nt*16 + l15;
        #pragma unroll
        for (int i = 0; i < 4; ++i) B[mt*16 + g*4 + i][col] = (f16)acc[mt][nt][i];
      }
    }
  }
  __syncthreads();

  // ---- temporal pooling: lam = softmax_t(h_t . h_63), z = sum lam_t * zt_t ----
  {
    int row = w*16 + (lane >> 2);
    int c0 = lane & 3;
    float dt = 0.f;
    #pragma unroll
    for (int j = 0; j < 8; ++j) {
      f16x8 va = *(const f16x8*)&B[row][j*32 + c0*8];
      f16x8 vb = *(const f16x8*)&B[63][j*32 + c0*8];
      #pragma unroll
      for (int e = 0; e < 8; ++e) dt += (float)va[e] * (float)vb[e];
    }
    dt += __shfl_xor(dt, 1); dt += __shfl_xor(dt, 2);
    if (c0 == 0) red[2 + row] = dt;
  }
  __syncthreads();
  if (tid < 64) {
    float v = red[2 + tid];
    float mx = v;
    #pragma unroll
    for (int off = 32; off >= 1; off >>= 1) mx = fmaxf(mx, __shfl_xor(mx, off));
    float e = __expf(v - mx);
    float sm = e;
    #pragma unroll
    for (int off = 32; off >= 1; off >>= 1) sm += __shfl_xor(sm, off);
    red[2 + tid] = e / sm;
  }
  __syncthreads();
  // z from the register-resident residual: reduce over rows held by g-groups
  {
    float zacc[4] = {0.f, 0.f, 0.f, 0.f};
    #pragma unroll
    for (int mt = 0; mt < 4; ++mt) {
      #pragma unroll
      for (int i = 0; i < 4; ++i) {
        float l = red[2 + mt*16 + g*4 + i];
        #pragma unroll
        for (int nt = 0; nt < 4; ++nt) zacc[nt] += l * (float)xres[mt][nt][i];
      }
    }
    #pragma unroll
    for (int nt = 0; nt < 4; ++nt) {
      zacc[nt] += __shfl_xor(zacc[nt], 16);
      zacc[nt] += __shfl_xor(zacc[nt], 32);
    }
    if (g == 0) {
      #pragma unroll
      for (int nt = 0; nt < 4; ++nt)
        zout[(size_t)n*256 + w*64 + nt*16 + l15] = zacc[nt];
    }
  }
}

// ---------------- K2: qk_in = [LN(z), LN(emb[id])] -> f16 ----------------
__global__ __launch_bounds__(256) void qkin_kernel(
    const float* __restrict__ z, const int* __restrict__ ids,
    const float* __restrict__ emb,
    const float* __restrict__ s_nx_s, const float* __restrict__ s_nx_b,
    const float* __restrict__ s_ni_s, const float* __restrict__ s_ni_b,
    f16* __restrict__ qk)
{
  int lane = threadIdx.x & 63;
  int w = threadIdx.x >> 6;
  int r = blockIdx.x*4 + w;
  const float* zr = z + (size_t)r*256;
  float v[4]; float s = 0.f, s2 = 0.f;
  #pragma unroll
  for (int j = 0; j < 4; ++j) { v[j] = zr[lane*4 + j]; s += v[j]; s2 += v[j]*v[j]; }
  #pragma unroll
  for (int off = 32; off >= 1; off >>= 1) { s += __shfl_xor(s, off); s2 += __shfl_xor(s2, off); }
  float mean = s*(1.f/256.f);
  float rstd = rsqrtf(s2*(1.f/256.f) - mean*mean + 1e-5f);
  f16* q = qk + (size_t)r*288;
  #pragma unroll
  for (int j = 0; j < 4; ++j) {
    int c = lane*4 + j;
    q[c] = (f16)((v[j] - mean)*rstd*s_nx_s[c] + s_nx_b[c]);
  }
  int id = ids[r];
  float e = (lane < 32) ? emb[id*32 + lane] : 0.f;
  float es = e, es2 = e*e;
  #pragma unroll
  for (int off = 16; off >= 1; off >>= 1) { es += __shfl_xor(es, off); es2 += __shfl_xor(es2, off); }
  if (lane < 32) {
    float m2 = es*(1.f/32.f);
    float rs2 = rsqrtf(es2*(1.f/32.f) - m2*m2 + 1e-5f);
    q[256 + lane] = (f16)((e - m2)*rs2*s_ni_s[lane] + s_ni_b[lane]);
  }
}

// ---------------- K3a: sq/sk = qk_in @ s_{q,k}w  (sq pre-scaled by 0.125) ------
__global__ __launch_bounds__(256) void sqk_kernel(const f16* __restrict__ qk,
    const f16* __restrict__ wbuf, f16* __restrict__ sq, f16* __restrict__ sk)
{
  const int tid = threadIdx.x, lane = tid & 63, w = tid >> 6, l15 = lane & 15, g = lane >> 4;
  const int isk = blockIdx.y;
  const f16* W = wbuf + (isk ? OFF_SKW : OFF_SQW);
  f16* out = isk ? sk : sq;
  const float scale = isk ? 1.f : 0.125f;
  const int r0 = blockIdx.x*64;
  f32x4 acc[4][4]; ZERO44(acc);
  #pragma unroll 2
  for (int ks = 0; ks < 9; ++ks) {
    int kc = ks*32 + g*8;
    f16x8 av[4], bv[4];
    #pragma unroll
    for (int j = 0; j < 4; ++j) av[j] = *(const f16x8*)(qk + (size_t)(r0 + j*16 + l15)*288 + kc);
    #pragma unroll
    for (int j = 0; j < 4; ++j) bv[j] = *(const f16x8*)(W + (size_t)(w*64 + j*16 + l15)*288 + kc);
    #pragma unroll
    for (int mt = 0; mt < 4; ++mt) {
      #pragma unroll
      for (int nt = 0; nt < 4; ++nt) acc[mt][nt] = MFMA32(av[mt], bv[nt], acc[mt][nt]);
    }
  }
  #pragma unroll
  for (int mt = 0; mt < 4; ++mt) {
    #pragma unroll
    for (int nt = 0; nt < 4; ++nt) {
      int col = w*64 + nt*16 + l15;
      #pragma unroll
      for (int i = 0; i < 4; ++i)
        out[(size_t)(r0 + mt*16 + g*4 + i)*256 + col] = (f16)(acc[mt][nt][i]*scale);
    }
  }
}

// ---------------- K3b: svT[d][key] = (zs @ s_vw)^T via transpose-GEMM ----------
__global__ __launch_bounds__(256) void svt_kernel(const f16* __restrict__ qk,
    const f16* __restrict__ wbuf, f16* __restrict__ svT)
{
  const int tid = threadIdx.x, lane = tid & 63, w = tid >> 6, l15 = lane & 15, g = lane >> 4;
  const int k0 = blockIdx.x*64;
  f32x4 acc[4][4]; ZERO44(acc);
  #pragma unroll 2
  for (int ks = 0; ks < 8; ++ks) {
    int kc = ks*32 + g*8;
    f16x8 av[4], bv[4];
    #pragma unroll
    for (int j = 0; j < 4; ++j) av[j] = *(const f16x8*)(wbuf + OFF_SVW + (size_t)(w*64 + j*16 + l15)*256 + kc);
    #pragma unroll
    for (int j = 0; j < 4; ++j) bv[j] = *(const f16x8*)(qk + (size_t)(k0 + j*16 + l15)*288 + kc);
    #pragma unroll
    for (int md = 0; md < 4; ++md) {
      #pragma unroll
      for (int nk = 0; nk < 4; ++nk) acc[md][nk] = MFMA32(av[md], bv[nk], acc[md][nk]);
    }
  }
  #pragma unroll
  for (int md = 0; md < 4; ++md) {
    #pragma unroll
    for (int nk = 0; nk < 4; ++nk) {
      int key = k0 + nk*16 + l15;
      #pragma unroll
      for (int i = 0; i < 4; ++i)
        svT[(size_t)(w*64 + md*16 + g*4 + i)*4096 + key] = (f16)acc[md][nk][i];
    }
  }
}

// ---------------- K4: flash cross-sectional attention (4096 keys) --------------
__global__ __launch_bounds__(256) void xattn_kernel(const f16* __restrict__ sq,
    const f16* __restrict__ sk, const f16* __restrict__ svT, f16* __restrict__ so)
{
  const int lane = threadIdx.x & 63, w = threadIdx.x >> 6, l15 = lane & 15, g = lane >> 4;
  const int h = blockIdx.y;
  const int q0 = blockIdx.x*64 + w*16;
  const f16* qp = sq + (size_t)q0*256 + h*64;
  f16x8 qf0 = *(const f16x8*)(qp + (size_t)l15*256 + g*8);
  f16x8 qf1 = *(const f16x8*)(qp + (size_t)l15*256 + 32 + g*8);
  f32x4 oacc[4];
  #pragma unroll
  for (int md = 0; md < 4; ++md) oacc[md] = zero4();
  float mrun = -1e30f, lrun = 0.f;
  for (int kt = 0; kt < 64; ++kt) {
    const f16* kp = sk + (size_t)kt*64*256 + h*64;
    f32x4 sacc[4];
    #pragma unroll
    for (int mt = 0; mt < 4; ++mt) sacc[mt] = zero4();
    #pragma unroll
    for (int mt = 0; mt < 4; ++mt) {
      f16x8 k0f = *(const f16x8*)(kp + (size_t)(mt*16 + l15)*256 + g*8);
      f16x8 k1f = *(const f16x8*)(kp + (size_t)(mt*16 + l15)*256 + 32 + g*8);
      sacc[mt] = MFMA32(k0f, qf0, sacc[mt]);
      sacc[mt] = MFMA32(k1f, qf1, sacc[mt]);
    }
    float tmax = -1e30f;
    #pragma unroll
    for (int mt = 0; mt < 4; ++mt) {
      #pragma unroll
      for (int i = 0; i < 4; ++i) tmax = fmaxf(tmax, sacc[mt][i]);
    }
    tmax = fmaxf(tmax, __shfl_xor(tmax, 16));
    tmax = fmaxf(tmax, __shfl_xor(tmax, 32));
    float mnew = fmaxf(mrun, tmax);
    float corr = __expf(mrun - mnew);
    float ts = 0.f;
    #pragma unroll
    for (int mt = 0; mt < 4; ++mt) {
      #pragma unroll
      for (int i = 0; i < 4; ++i) { float e = __expf(sacc[mt][i] - mnew); sacc[mt][i] = e; ts += e; }
    }
    ts += __shfl_xor(ts, 16);
    ts += __shfl_xor(ts, 32);
    lrun = lrun*corr + ts;
    mrun = mnew;
    f16x4 pf[4];
    #pragma unroll
    for (int mt = 0; mt < 4; ++mt) {
      #pragma unroll
      for (int i = 0; i < 4; ++i) pf[mt][i] = (f16)sacc[mt][i];
    }
    #pragma unroll
    for (int md = 0; md < 4; ++md) {
      #pragma unroll
      for (int i = 0; i < 4; ++i) oacc[md][i] *= corr;
    }
    const f16* vp = svT + (size_t)h*64*4096 + kt*64;
    #pragma unroll
    for (int ks = 0; ks < 4; ++ks) {
      #pragma unroll
      for (int md = 0; md < 4; ++md) {
        f16x4 vf = *(const f16x4*)(vp + (size_t)(md*16 + l15)*4096 + ks*16 + g*4);
        oacc[md] = MFMA16(vf, pf[ks], oacc[md]);
      }
    }
  }
  float rinv = 1.f / lrun;
  #pragma unroll
  for (int md = 0; md < 4; ++md) {
    f16x4 ov;
    #pragma unroll
    for (int i = 0; i < 4; ++i) ov[i] = (f16)(oacc[md][i]*rinv);
    *(f16x4*)(so + (size_t)(q0 + l15)*256 + h*64 + md*16 + g*4) = ov;
  }
}

// ---------------- K5: zt = z + so@s_ow+b -> LN -> FFN -> dec -------------------
__global__ __launch_bounds__(256, 2) void final_kernel(
    const f16* __restrict__ so, const float* __restrict__ z,
    const f16* __restrict__ wbuf,
    const float* __restrict__ s_ob,
    const float* __restrict__ s_nf_s, const float* __restrict__ s_nf_b,
    const float* __restrict__ s_f1b, const float* __restrict__ s_f2b,
    const float* __restrict__ dec_w, const float* __restrict__ dec_b,
    float* __restrict__ out)
{
  __shared__ __align__(16) f16 zb[64][264];
  __shared__ __align__(16) f16 yb[64][264];
  __shared__ __align__(16) f16 ub[64][72];
  const int tid = threadIdx.x, lane = tid & 63, w = tid >> 6, l15 = lane & 15, g = lane >> 4;
  const int r0 = blockIdx.x*64;
  {
    f32x4 acc[4][4]; ZERO44(acc);
    #pragma unroll 2
    for (int ks = 0; ks < 8; ++ks) {
      int kc = ks*32 + g*8;
      f16x8 av[4], bv[4];
      #pragma unroll
      for (int j = 0; j < 4; ++j) av[j] = *(const f16x8*)(so + (size_t)(r0 + j*16 + l15)*256 + kc);
      #pragma unroll
      for (int j = 0; j < 4; ++j) bv[j] = *(const f16x8*)(wbuf + OFF_SOW + (size_t)(w*64 + j*16 + l15)*256 + kc);
      #pragma unroll
      for (int mt = 0; mt < 4; ++mt) {
        #pragma unroll
        for (int nt = 0; nt < 4; ++nt) acc[mt][nt] = MFMA32(av[mt], bv[nt], acc[mt][nt]);
      }
    }
    #pragma unroll
    for (int mt = 0; mt < 4; ++mt) {
      #pragma unroll
      for (int nt = 0; nt < 4; ++nt) {
        int col = w*64 + nt*16 + l15;
        #pragma unroll
        for (int i = 0; i < 4; ++i) {
          int row = mt*16 + g*4 + i;
          zb[row][col] = (f16)(z[(size_t)(r0 + row)*256 + col] + acc[mt][nt][i] + s_ob[col]);
        }
      }
    }
  }
  __syncthreads();
  ln64v(zb, yb, s_nf_s, s_nf_b, w, lane);
  __syncthreads();
  ffn_block(zb, yb, ub, wbuf + OFF_SF1, wbuf + OFF_SF2, s_f1b, s_f2b, w, l15, g);
  __syncthreads();
  {
    int row = w*16 + (lane >> 2), c0 = lane & 3;
    float dt = 0.f;
    #pragma unroll
    for (int j = 0; j < 8; ++j) {
      f16x8 va = *(const f16x8*)&zb[row][j*32 + c0*8];
      #pragma unroll
      for (int e = 0; e < 8; ++e) dt += (float)va[e]*dec_w[j*32 + c0*8 + e];
    }
    dt += __shfl_xor(dt, 1); dt += __shfl_xor(dt, 2);
    if (c0 == 0) out[r0 + row] = dt + dec_b[0];
  }
}

// ---------------- launch ----------------
extern "C" void kernel_launch(void* const* d_in, const int* in_sizes, int n_in,
                              void* d_out, int out_size, void* d_ws, size_t ws_size,
                              hipStream_t stream)
{
  const int*   ids    = (const int*)  d_in[0];
  const float* stock  = (const float*)d_in[1];
  const float* market = (const float*)d_in[2];
  const float* emb    = (const float*)d_in[3];
  const float* gate_w = (const float*)d_in[4];
  const float* gate_b = (const float*)d_in[5];

  char* ws = (char*)d_ws;
  f16*   wbuf = (f16*)ws;
  float* pe   = (float*)(ws + PE_B);
  float* zbuf = (float*)(ws + Z_B);
  f16*   qk   = (f16*)(ws + QK_B);
  f16*   sq   = (f16*)(ws + SQ_B);
  f16*   sk   = (f16*)(ws + SK_B);
  f16*   svT  = (f16*)(ws + SVT_B);
  f16*   so   = (f16*)(ws + SO_B);

  PrepArgs pa;
  const int srcIdx[14] = {6,8,9,10,11,17,19,36,21,22,23,24,32,34};
  const int Ks[14]   = {158,256,256,256,256,256,256,256,288,288,256,256,256,256};
  const int Kps[14]  = {160,256,256,256,256,256,256,256,288,288,256,256,256,256};
  const int offs[14] = {(int)OFF_PROJ,(int)OFF_QW,(int)OFF_KW,(int)OFF_VW,(int)OFF_OW,
                        (int)OFF_F1,(int)OFF_F2,(int)OFF_TA,(int)OFF_SQW,(int)OFF_SKW,
                        (int)OFF_SVW,(int)OFF_SOW,(int)OFF_SF1,(int)OFF_SF2};
  for (int i = 0; i < 14; ++i) {
    pa.src[i] = (const float*)d_in[srcIdx[i]];
    pa.K[i] = Ks[i]; pa.Kp[i] = Kps[i]; pa.off[i] = offs[i];
  }

  prep_kernel<<<dim3(64,15), dim3(256), 0, stream>>>(pa, wbuf, pe);
  temporal_kernel<<<dim3(4096), dim3(256), 0, stream>>>(
      stock, market, gate_w, gate_b,
      (const float*)d_in[7],  (const float*)d_in[12],
      (const float*)d_in[13], (const float*)d_in[14],
      (const float*)d_in[15], (const float*)d_in[16],
      (const float*)d_in[18], (const float*)d_in[20],
      wbuf, pe, zbuf);
  qkin_kernel<<<dim3(1024), dim3(256), 0, stream>>>(
      zbuf, ids, emb,
      (const float*)d_in[26], (const float*)d_in[27],
      (const float*)d_in[28], (const float*)d_in[29], qk);
  sqk_kernel<<<dim3(64,2), dim3(256), 0, stream>>>(qk, wbuf, sq, sk);
  svt_kernel<<<dim3(64), dim3(256), 0, stream>>>(qk, wbuf, svT);
  xattn_kernel<<<dim3(64,4), dim3(256), 0, stream>>>(sq, sk, svT, so);
  final_kernel<<<dim3(64), dim3(256), 0, stream>>>(
      so, zbuf, wbuf,
      (const float*)d_in[25], (const float*)d_in[30], (const float*)d_in[31],
      (const float*)d_in[33], (const float*)d_in[35],
      (const float*)d_in[37], (const float*)d_in[38], (float*)d_out);
}